// Round 6
// baseline (479.688 us; speedup 1.0000x reference)
//
#include <hip/hip_runtime.h>
#include <hip/hip_bf16.h>

// ---------------------------------------------------------------------------
// FusionCrossAttention: out = softmax((x Wq^T)(kv Wk^T)^T / sqrt(hd)) (kv Wv^T) Wo^T
// B=4, T_q=1024, T_kv=4096, D=1024, H=16, hd=64
// Intermediates bf16, accumulation f32 via MFMA. Softmax scale (and log2e)
// folded into the W_q bf16 conversion.
// ---------------------------------------------------------------------------

typedef __attribute__((ext_vector_type(4))) float f32x4;
typedef __attribute__((ext_vector_type(16))) float f32x16;
typedef __attribute__((ext_vector_type(8))) short bf16x8;

__device__ __forceinline__ unsigned short f2bf(float f) {
  unsigned u = __float_as_uint(f);
  u = (u + 0x7fffu + ((u >> 16) & 1u)) >> 16;   // round-to-nearest-even
  return (unsigned short)u;
}

// v_permlane32_swap_b32: x' = [x(0:31), y(0:31)], y' = [x(32:63), y(32:63)]
__device__ __forceinline__ void pl32swap(unsigned& x, unsigned& y) {
  asm volatile("v_permlane32_swap_b32 %0, %1" : "+v"(x), "+v"(y));
}

#define GLD_LDS16(g, l)                                                     \
  __builtin_amdgcn_global_load_lds(                                        \
      (const __attribute__((address_space(1))) unsigned int*)(const void*)(g), \
      (__attribute__((address_space(3))) unsigned int*)(void*)(l), 16, 0, 0)

// ---------------------------------------------------------------------------
// Fused f32 -> bf16 conversion for all six inputs (one launch).
// W_q additionally scaled by 1/sqrt(64) * log2(e) BEFORE rounding.
// ---------------------------------------------------------------------------
__global__ void cvt_all(const float* __restrict__ q, const float* __restrict__ kv,
                        const float* __restrict__ wq, const float* __restrict__ wk,
                        const float* __restrict__ wv, const float* __restrict__ wo,
                        unsigned short* __restrict__ q_bf,
                        unsigned short* __restrict__ kv_bf,
                        unsigned short* __restrict__ wq_bf,
                        unsigned short* __restrict__ wk_bf,
                        unsigned short* __restrict__ wv_bf,
                        unsigned short* __restrict__ wo_bf) {
  const int QN = 4194304, KVN = 16777216, WN = 1048576;
  const float SC = 0.125f * 1.44269504088896f;
  int total_quads = (QN + KVN + 4 * WN) >> 2;
  int stride = gridDim.x * blockDim.x;
  for (int t = blockIdx.x * blockDim.x + threadIdx.x; t < total_quads; t += stride) {
    int i = t << 2;
    const float* src;
    unsigned short* dst;
    float sc = 1.0f;
    int off;
    if (i < QN) { src = q; dst = q_bf; off = i; }
    else if (i < QN + KVN) { src = kv; dst = kv_bf; off = i - QN; }
    else if (i < QN + KVN + WN) { src = wq; dst = wq_bf; off = i - QN - KVN; sc = SC; }
    else if (i < QN + KVN + 2 * WN) { src = wk; dst = wk_bf; off = i - QN - KVN - WN; }
    else if (i < QN + KVN + 3 * WN) { src = wv; dst = wv_bf; off = i - QN - KVN - 2 * WN; }
    else { src = wo; dst = wo_bf; off = i - QN - KVN - 3 * WN; }
    float4 v = *(const float4*)(src + off);
    ushort4 r;
    r.x = f2bf(v.x * sc); r.y = f2bf(v.y * sc);
    r.z = f2bf(v.z * sc); r.w = f2bf(v.w * sc);
    *(ushort4*)(dst + off) = r;
  }
}

// ---------------------------------------------------------------------------
// 128x128x(K) GEMM, C[i][j] = sum_k A[i][k] * Bt[j][k]   (B^T input layout)
// m97 structure (unchanged this round).
// ---------------------------------------------------------------------------
template <int WRITE_BF16>
__global__ __launch_bounds__(256) void gemm_bt(
    const unsigned short* __restrict__ A, const unsigned short* __restrict__ Bt,
    void* __restrict__ Cp, int M, int N, int K, int ldc) {
  __shared__ __align__(16) unsigned short Ash[4096];  // [128][32]
  __shared__ __align__(16) unsigned short Bsh[4096];  // [128][32]

  int tiles_n = N >> 7;
  int nwg = gridDim.x;
  int wg = blockIdx.x;
  int cpx = nwg >> 3;
  wg = (wg & 7) * cpx + (wg >> 3);          // XCD-aware swizzle
  int tm = wg / tiles_n, tn = wg - tm * tiles_n;

  int tid = threadIdx.x;
  int lane = tid & 63, wave = tid >> 6;
  int wr = wave >> 1, wc = wave & 1;
  int brow = tm << 7, bcol = tn << 7;

  int fr = lane & 15, fg = lane >> 4;
  int swz = (fr >> 1) & 3;

  int srow = lane >> 2;
  int sg = (lane & 3) ^ ((srow >> 1) & 3);

  const unsigned short* aG0 = A + (size_t)(brow + wave * 32 + srow) * K + sg * 8;
  const unsigned short* aG1 = A + (size_t)(brow + wave * 32 + 16 + srow) * K + sg * 8;
  const unsigned short* bG0 = Bt + (size_t)(bcol + wave * 32 + srow) * K + sg * 8;
  const unsigned short* bG1 = Bt + (size_t)(bcol + wave * 32 + 16 + srow) * K + sg * 8;
  unsigned short* aL0 = Ash + wave * 1024;
  unsigned short* aL1 = Ash + wave * 1024 + 512;
  unsigned short* bL0 = Bsh + wave * 1024;
  unsigned short* bL1 = Bsh + wave * 1024 + 512;

  const f32x4 zero4 = {0.f, 0.f, 0.f, 0.f};
  f32x4 acc[4][4];
#pragma unroll
  for (int m = 0; m < 4; ++m)
#pragma unroll
    for (int n = 0; n < 4; ++n) acc[m][n] = zero4;

  for (int k0 = 0; k0 < K; k0 += 32) {
    GLD_LDS16(aG0 + k0, aL0);
    GLD_LDS16(aG1 + k0, aL1);
    GLD_LDS16(bG0 + k0, bL0);
    GLD_LDS16(bG1 + k0, bL1);
    __syncthreads();

    bf16x8 af[4], bfr[4];
#pragma unroll
    for (int m = 0; m < 4; ++m) {
      int r = wr * 64 + m * 16 + fr;
      af[m] = *(const bf16x8*)(Ash + r * 32 + ((fg ^ swz) * 8));
    }
#pragma unroll
    for (int n = 0; n < 4; ++n) {
      int r = wc * 64 + n * 16 + fr;
      bfr[n] = *(const bf16x8*)(Bsh + r * 32 + ((fg ^ swz) * 8));
    }
#pragma unroll
    for (int m = 0; m < 4; ++m)
#pragma unroll
      for (int n = 0; n < 4; ++n)
        acc[m][n] =
            __builtin_amdgcn_mfma_f32_16x16x32_bf16(af[m], bfr[n], acc[m][n], 0, 0, 0);
    __syncthreads();
  }

  int crow = brow + wr * 64 + fg * 4;
  int ccol = bcol + wc * 64 + fr;
#pragma unroll
  for (int m = 0; m < 4; ++m)
#pragma unroll
    for (int n = 0; n < 4; ++n)
#pragma unroll
      for (int j = 0; j < 4; ++j) {
        size_t off = (size_t)(crow + m * 16 + j) * ldc + (ccol + n * 16);
        if (WRITE_BF16)
          ((unsigned short*)Cp)[off] = f2bf(acc[m][n][j]);
        else
          ((float*)Cp)[off] = acc[m][n][j];
      }
}

// ---------------------------------------------------------------------------
// Flash attention v6: swapped QK^T + 32x32x16 MFMA, in-register softmax,
// double-buffered 2-phase staging (T3 minimum recipe), correct bank swizzle.
// Grid: 512 blocks = (b:4, h:16, qtile:8 of 128 rows), XCD-swizzled.
// Block: 256 thr / 4 waves, each wave owns 32 q-rows; all share one KV tile.
// KVBLK=128, 32 iters, ONE barrier per iter: prefetch tile t+1 into buf^1,
// compute tile t (32 ds_read_b128 + 40 MFMA + softmax), then barrier
// (vmcnt drain happens AFTER compute -> load latency hidden).
// Swizzle (both tiles): 16B slot = granule ^ (row&7) -> each group of 8
// consecutive lanes (q5 consecutive) hits 8 distinct slots = conflict-free.
// LDS 64 KB (2 x [K 128x64 + Vt 64x128]) -> 2 blocks/CU.
// ---------------------------------------------------------------------------
__global__ __launch_bounds__(256) void attn_fwd(
    const unsigned short* __restrict__ qp,  // (4096, 1024), pre-scaled by SC
    const unsigned short* __restrict__ kp,  // (16384, 1024)
    const unsigned short* __restrict__ vt,  // (1024, 16384) = V^T per (b,h)
    unsigned short* __restrict__ ao) {      // (4096, 1024)
  __shared__ __align__(16) unsigned short SMEM[32768];  // 64 KB, 2 buffers

  int idx = (blockIdx.x & 7) * 64 + (blockIdx.x >> 3);
  int qt = idx & 7;
  int h = (idx >> 3) & 15;
  int b = idx >> 7;
  int tid = threadIdx.x;
  int lane = tid & 63, w = tid >> 6;
  int q5 = lane & 31, hi = lane >> 5;

  // ---- Q fragments (B-operand, 32x32x16): lane q5, k = s*16 + hi*8 + e ----
  const unsigned short* qptr =
      qp + (size_t)(b * 1024 + qt * 128 + w * 32 + q5) * 1024 + h * 64 + hi * 8;
  bf16x8 qf[4];
#pragma unroll
  for (int s = 0; s < 4; ++s) qf[s] = *(const bf16x8*)(qptr + s * 16);

  bf16x8 ones;
#pragma unroll
  for (int e = 0; e < 8; ++e) ones[e] = (short)0x3F80;  // 1.0 bf16

  f32x16 O0, O1, rsum;
#pragma unroll
  for (int r = 0; r < 16; ++r) { O0[r] = 0.f; O1[r] = 0.f; rsum[r] = 0.f; }
  float mrun = -1e30f;

  // ---- staging sources (pre-swizzled: dest slot g holds granule g^(row&7)) --
  // K [128][64]: issue i covers rows i*32 + (tid>>3); dest = buf + i*2048 + w*512
  int gk = (tid & 7) ^ ((tid >> 3) & 7);
  const unsigned short* kS =
      kp + (size_t)(b * 4096 + (tid >> 3)) * 1024 + h * 64 + gk * 8;
  // Vt [64][128]: issue i covers rows i*16 + (tid>>4); dest = buf+8192+i*2048+w*512
  int gv = (tid & 15) ^ ((tid >> 4) & 7);
  const unsigned short* vS =
      vt + (size_t)(h * 64 + (tid >> 4)) * 16384 + b * 4096 + gv * 8;

  // ---- read-side slot offsets: slot = (2s + hi) ^ (q5 & 7) ----
  int hx = hi ^ (q5 & 7);
  int koff[4];
#pragma unroll
  for (int s = 0; s < 4; ++s) koff[s] = q5 * 64 + (((2 * s) ^ hx) * 8);
  int voff[8];
#pragma unroll
  for (int s = 0; s < 8; ++s) voff[s] = (((2 * s) ^ hx) * 8);

#define STAGE(buf, kadv, vadv)                                                \
  {                                                                           \
    _Pragma("unroll")                                                         \
    for (int i = 0; i < 4; ++i) {                                             \
      GLD_LDS16(kS + (kadv) + i * 32768, (buf) + i * 2048 + w * 512);         \
      GLD_LDS16(vS + (vadv) + i * 262144, (buf) + 8192 + i * 2048 + w * 512); \
    }                                                                         \
  }

  // prologue: stage tile 0 into buffer 0
  STAGE(SMEM, 0, 0);
  __syncthreads();

  for (int it = 0; it < 32; ++it) {
    const unsigned short* cur = SMEM + (it & 1) * 16384;
    // prefetch next tile into the other buffer (its readers finished at the
    // barrier ending iteration it-1)
    if (it < 31) {
      unsigned short* nxt = SMEM + ((it + 1) & 1) * 16384;
      STAGE(nxt, (size_t)(it + 1) * 131072, (it + 1) * 128);
    }

    const unsigned short* Kb = cur;          // [128][64]
    const unsigned short* Vb = cur + 8192;   // [64][128]

    // ---- S^T = K Q^T : 4 kv-subtiles x 4 d-slices ----
    f32x16 S[4];
#pragma unroll
    for (int kt = 0; kt < 4; ++kt)
#pragma unroll
      for (int r = 0; r < 16; ++r) S[kt][r] = 0.f;
    __builtin_amdgcn_s_setprio(1);
#pragma unroll
    for (int kt = 0; kt < 4; ++kt)
#pragma unroll
      for (int s = 0; s < 4; ++s) {
        bf16x8 kf = *(const bf16x8*)(Kb + kt * 2048 + koff[s]);
        S[kt] = __builtin_amdgcn_mfma_f32_32x32x16_bf16(kf, qf[s], S[kt], 0, 0, 0);
      }
    __builtin_amdgcn_s_setprio(0);

    // ---- row max: tree over 64 values + one cross-half shuffle ----
    float tm[16];
#pragma unroll
    for (int r = 0; r < 16; ++r)
      tm[r] = fmaxf(fmaxf(S[0][r], S[1][r]), fmaxf(S[2][r], S[3][r]));
#pragma unroll
    for (int st = 8; st >= 1; st >>= 1)
#pragma unroll
      for (int r = 0; r < st; ++r) tm[r] = fmaxf(tm[r], tm[r + st]);
    float cmax = fmaxf(tm[0], __shfl_xor(tm[0], 32));

    // ---- rescale only when running max grows (skip is exact) ----
    if (__any(cmax > mrun)) {
      float mn = fmaxf(mrun, cmax);
      float fsc = exp2f(mrun - mn);
      mrun = mn;
      rsum[0] *= fsc;  // only [0] is ever read
#pragma unroll
      for (int r = 0; r < 16; ++r) { O0[r] *= fsc; O1[r] *= fsc; }
    }

    // ---- per kv-subtile: exp2, pack to B-frags in-register, rsum + PV ----
#pragma unroll
    for (int kt = 0; kt < 4; ++kt) {
      float p[16];
#pragma unroll
      for (int r = 0; r < 16; ++r) p[r] = exp2f(S[kt][r] - mrun);
      unsigned u[8];
#pragma unroll
      for (int i2 = 0; i2 < 8; ++i2) {
        __hip_bfloat162 pk =
            __float22bfloat162_rn(float2{p[2 * i2], p[2 * i2 + 1]});
        u[i2] = *reinterpret_cast<unsigned*>(&pk);
      }
      pl32swap(u[0], u[2]); pl32swap(u[1], u[3]);
      pl32swap(u[4], u[6]); pl32swap(u[5], u[7]);
      union PU { unsigned uu[4]; bf16x8 v; };
      PU a0; a0.uu[0] = u[0]; a0.uu[1] = u[1]; a0.uu[2] = u[2]; a0.uu[3] = u[3];
      PU a1; a1.uu[0] = u[4]; a1.uu[1] = u[5]; a1.uu[2] = u[6]; a1.uu[3] = u[7];
      bf16x8 pf0 = a0.v, pf1 = a1.v;

      __builtin_amdgcn_s_setprio(1);
      rsum = __builtin_amdgcn_mfma_f32_32x32x16_bf16(ones, pf0, rsum, 0, 0, 0);
      rsum = __builtin_amdgcn_mfma_f32_32x32x16_bf16(ones, pf1, rsum, 0, 0, 0);
      bf16x8 vf;
      vf = *(const bf16x8*)(Vb + q5 * 128 + voff[2 * kt + 0]);
      O0 = __builtin_amdgcn_mfma_f32_32x32x16_bf16(vf, pf0, O0, 0, 0, 0);
      vf = *(const bf16x8*)(Vb + q5 * 128 + voff[2 * kt + 1]);
      O0 = __builtin_amdgcn_mfma_f32_32x32x16_bf16(vf, pf1, O0, 0, 0, 0);
      vf = *(const bf16x8*)(Vb + 4096 + q5 * 128 + voff[2 * kt + 0]);
      O1 = __builtin_amdgcn_mfma_f32_32x32x16_bf16(vf, pf0, O1, 0, 0, 0);
      vf = *(const bf16x8*)(Vb + 4096 + q5 * 128 + voff[2 * kt + 1]);
      O1 = __builtin_amdgcn_mfma_f32_32x32x16_bf16(vf, pf1, O1, 0, 0, 0);
      __builtin_amdgcn_s_setprio(0);
    }

    __syncthreads();  // drains prefetch vmcnt + protects buffers
  }
#undef STAGE

  // ---- normalize + store: lane q5 owns one q-row; d = dt*32+8*j2+4*hi+j ----
  float inv = 1.0f / rsum[0];
  size_t obase = (size_t)(b * 1024 + qt * 128 + w * 32 + q5) * 1024 + h * 64;
#pragma unroll
  for (int j2 = 0; j2 < 4; ++j2) {
    ushort4 pk;
    pk.x = f2bf(O0[4 * j2 + 0] * inv);
    pk.y = f2bf(O0[4 * j2 + 1] * inv);
    pk.z = f2bf(O0[4 * j2 + 2] * inv);
    pk.w = f2bf(O0[4 * j2 + 3] * inv);
    *(ushort4*)(ao + obase + j2 * 8 + hi * 4) = pk;
  }
#pragma unroll
  for (int j2 = 0; j2 < 4; ++j2) {
    ushort4 pk;
    pk.x = f2bf(O1[4 * j2 + 0] * inv);
    pk.y = f2bf(O1[4 * j2 + 1] * inv);
    pk.z = f2bf(O1[4 * j2 + 2] * inv);
    pk.w = f2bf(O1[4 * j2 + 3] * inv);
    *(ushort4*)(ao + obase + 32 + j2 * 8 + hi * 4) = pk;
  }
}

// ---------------------------------------------------------------------------
// Launcher. Workspace layout (128 MiB):
//   [0,8)    q_bf     [8,40)  kv_bf    [40,48) weights bf16 x4
//   [48,56)  qproj    [56,88) kproj    [88,120) v^T proj   [120,128) attn out
// ---------------------------------------------------------------------------
extern "C" void kernel_launch(void* const* d_in, const int* in_sizes, int n_in,
                              void* d_out, int out_size, void* d_ws, size_t ws_size,
                              hipStream_t stream) {
  const float* query = (const float*)d_in[0];
  const float* kvs = (const float*)d_in[1];
  const float* wq = (const float*)d_in[2];
  const float* wk = (const float*)d_in[3];
  const float* wv = (const float*)d_in[4];
  const float* wo = (const float*)d_in[5];
  float* out = (float*)d_out;
  char* ws = (char*)d_ws;
  const size_t MB = 1ull << 20;

  unsigned short* q_bf = (unsigned short*)(ws + 0 * MB);
  unsigned short* kv_bf = (unsigned short*)(ws + 8 * MB);
  unsigned short* wq_bf = (unsigned short*)(ws + 40 * MB);
  unsigned short* wk_bf = (unsigned short*)(ws + 42 * MB);
  unsigned short* wv_bf = (unsigned short*)(ws + 44 * MB);
  unsigned short* wo_bf = (unsigned short*)(ws + 46 * MB);
  unsigned short* qp = (unsigned short*)(ws + 48 * MB);
  unsigned short* kp = (unsigned short*)(ws + 56 * MB);
  unsigned short* vt = (unsigned short*)(ws + 88 * MB);
  unsigned short* ao = (unsigned short*)(ws + 120 * MB);

  cvt_all<<<2048, 256, 0, stream>>>(query, kvs, wq, wk, wv, wo, q_bf, kv_bf,
                                    wq_bf, wk_bf, wv_bf, wo_bf);

  // q = query @ (Wq*SC)^T       (4096 x 1024)
  gemm_bt<1><<<256, 256, 0, stream>>>(q_bf, wq_bf, qp, 4096, 1024, 1024, 1024);
  // k = kv @ Wk^T               (16384 x 1024)
  gemm_bt<1><<<1024, 256, 0, stream>>>(kv_bf, wk_bf, kp, 16384, 1024, 1024, 1024);
  // v^T = Wv @ kv^T             (1024 x 16384)
  gemm_bt<1><<<1024, 256, 0, stream>>>(wv_bf, kv_bf, vt, 1024, 16384, 1024, 16384);

  attn_fwd<<<512, 256, 0, stream>>>(qp, kp, vt, ao);

  // out = attn_out @ Wo^T       (4096 x 1024) f32
  gemm_bt<0><<<256, 256, 0, stream>>>(ao, wo_bf, out, 4096, 1024, 1024, 1024);
}